// Round 10
// baseline (594.764 us; speedup 1.0000x reference)
//
#include <hip/hip_runtime.h>
#include <stdint.h>

typedef unsigned int u32;
typedef unsigned long long u64;
typedef unsigned short u16;
typedef unsigned char u8;

#define B_IMG 8
#define N_BOX 2000
#define N_PAD 2048
#define C_DIM 4096
#define HIDN 42
#define NCLS 20
#define NWRD 64   // 2048 bits per adjacency row
#define NPAIR 136 // 16*17/2 lower-triangle 128-tiles
#define KSPLIT 4
#define YG_LSTEPS 32   // (4096/KSPLIT)/32 steps per wave

using f32x4 = __attribute__((ext_vector_type(4))) float;
using s16x8 = __attribute__((ext_vector_type(8))) short;

__device__ __forceinline__ u32 f2bf(float f) {   // fp32 -> bf16 RNE
    u32 u = __float_as_uint(f);
    u += 0x7FFFu + ((u >> 16) & 1u);
    return u >> 16;
}

#define GLOAD_LDS16(g, l)                                                     \
    __builtin_amdgcn_global_load_lds(                                         \
        (const __attribute__((address_space(1))) void*)(g),                   \
        (__attribute__((address_space(3))) void*)(l), 16, 0, 0)

// ---------------------------------------------------------------- wt_build
__global__ __launch_bounds__(256) void wt_build(const float* __restrict__ Wc,
                                                const float* __restrict__ Wd,
                                                u16* __restrict__ Wth,
                                                u16* __restrict__ Wtl) {
    int g = blockIdx.x * 256 + threadIdx.x;
    if (g >= 96 * C_DIM) return;
    int k = g & (C_DIM - 1);
    int c = g >> 12;
    float v = 0.0f;
    if (c < HIDN) v = Wc[k * HIDN + c];
    else if (c < 2 * HIDN) v = Wd[k * HIDN + (c - HIDN)];
    u32 hb = f2bf(v);
    float hf = __uint_as_float(hb << 16);
    u32 lb = f2bf(v - hf);
    Wth[g] = (u16)hb;
    Wtl[g] = (u16)lb;
}

// ---------------------------------------------------------------- sf_pad
__global__ __launch_bounds__(256) void sf_pad(u8* __restrict__ SF,
                                              float* __restrict__ NRM) {
    int row = blockIdx.x;                  // 0..383
    int img = row / 48, n = N_BOX + row % 48;
    uint4* p = (uint4*)(SF + ((size_t)img * N_PAD + n) * C_DIM);
    uint4 z = make_uint4(0, 0, 0, 0);
    p[threadIdx.x] = z;                    // 256 x 16B = 4096 B
    if (threadIdx.x == 0) NRM[(size_t)img * N_PAD + n] = 1e9f;
}

// ---------------------------------------------------------------- rowstats (fallback only)
__global__ __launch_bounds__(256) void rowstats(const float* __restrict__ x,
                                                float* __restrict__ inv_sum,
                                                u8* __restrict__ sf,
                                                float* __restrict__ nrm) {
    int r = blockIdx.x;
    int t = threadIdx.x;
    u8* sfrow = sf + (size_t)r * C_DIM;
    if (r >= N_BOX) {
        uint4 z = make_uint4(0, 0, 0, 0);
        uint4* p = (uint4*)sfrow;
        for (int i = t; i < C_DIM / 16; i += 256) p[i] = z;
        if (t == 0) nrm[r] = 1e9f;
        return;
    }
    const float4* xr = (const float4*)(x + (size_t)r * C_DIM);
    float4 v[4];
    float s = 0.0f, ss = 0.0f;
#pragma unroll
    for (int i = 0; i < 4; i++) {
        v[i] = xr[t + 256 * i];
        s += v[i].x + v[i].y + v[i].z + v[i].w;
        ss += v[i].x * v[i].x + v[i].y * v[i].y + v[i].z * v[i].z + v[i].w * v[i].w;
    }
    __shared__ float red[4][2];
#pragma unroll
    for (int off = 32; off; off >>= 1) {
        s += __shfl_down(s, off);
        ss += __shfl_down(ss, off);
    }
    int wid = t >> 6, lane = t & 63;
    if (lane == 0) { red[wid][0] = s; red[wid][1] = ss; }
    __syncthreads();
    s  = red[0][0] + red[1][0] + red[2][0] + red[3][0];
    ss = red[0][1] + red[1][1] + red[2][1] + red[3][1];
    if (t == 0) {
        inv_sum[r] = (s == 0.0f) ? 0.0f : 1.0f / s;
        nrm[r] = sqrtf(ss);
    }
    u32* sp = (u32*)sfrow;
#pragma unroll
    for (int i = 0; i < 4; i++) {
        float4 w = v[i];
        u32 pk = __builtin_amdgcn_cvt_pk_fp8_f32(4.f * w.x, 4.f * w.y, 0, false);
        pk = __builtin_amdgcn_cvt_pk_fp8_f32(4.f * w.z, 4.f * w.w, pk, true);
        sp[t + 256 * i] = pk;
    }
}

// ---------------------------------------------------------------- gemm_sim
__global__ __launch_bounds__(256) void gemm_sim(const u8* __restrict__ sf_all,
                                                const float* __restrict__ nrm_all,
                                                u32* __restrict__ bits_all) {
    __shared__ __align__(16) char smem[32768];   // [A0 8K][B0 8K][A1 8K][B1 8K]
    char* tmat = smem;                           // epilogue reuse [128][132]

    int z = blockIdx.z;
    const u8* sf = sf_all + (size_t)z * N_PAD * C_DIM;
    const float* nrm = nrm_all + (size_t)z * N_PAD;
    u32* bits = bits_all + (size_t)z * N_PAD * NWRD;

    int p = blockIdx.x;
    int bi = (int)((sqrtf(8.0f * p + 1.0f) - 1.0f) * 0.5f);
    while (bi * (bi + 1) / 2 > p) bi--;
    while ((bi + 1) * (bi + 2) / 2 <= p) bi++;
    int bj = p - bi * (bi + 1) / 2;

    int t = threadIdx.x;
    int lane = t & 63;
    int w = t >> 6;
    int wm = w >> 1, wn = w & 1;
    int tr0 = bi * 128, tc0 = bj * 128;
    f32x4 acc[4][4] = {};
    int q = lane & 15, g = lane >> 4;
    int swz = (q >> 1) & 3;
    int g8 = (g & 1) * 8, gh = g >> 1;

    auto stage = [&](int it, int b) {
        int k0 = it * 64;
        u8* As = (u8*)smem + b * 16384;
        u8* Bs = As + 8192;
#pragma unroll
        for (int i = 0; i < 2; i++) {
            int ci = t + 256 * i;            // 0..511 16B-chunks
            int r = ci >> 2, c16 = ci & 3;
            int sc16 = c16 ^ ((r >> 1) & 3);
            GLOAD_LDS16(sf + ((size_t)(tr0 + r) << 12) + k0 + sc16 * 16,
                        As + ci * 16);
            GLOAD_LDS16(sf + ((size_t)(tc0 + r) << 12) + k0 + sc16 * 16,
                        Bs + ci * 16);
        }
    };

    stage(0, 0);
    __syncthreads();
    for (int it = 0; it < 64; ++it) {
        int cur = it & 1;
        if (it + 1 < 64) stage(it + 1, cur ^ 1);   // prefetch under MFMA
        const u8* As = (const u8*)smem + cur * 16384;
        const u8* Bs = As + 8192;
#pragma unroll
        for (int kk = 0; kk < 2; kk++) {
            int boff = ((2 * kk + gh) ^ swz) * 16 + g8;
            long long a[4], b[4];
#pragma unroll
            for (int m = 0; m < 4; m++)
                a[m] = *(const long long*)(As + (wm * 64 + m * 16 + q) * 64 + boff);
#pragma unroll
            for (int n = 0; n < 4; n++)
                b[n] = *(const long long*)(Bs + (wn * 64 + n * 16 + q) * 64 + boff);
#pragma unroll
            for (int m = 0; m < 4; m++)
#pragma unroll
                for (int n = 0; n < 4; n++)
                    acc[m][n] = __builtin_amdgcn_mfma_f32_16x16x32_fp8_fp8(a[m], b[n], acc[m][n], 0, 0, 0);
        }
        __syncthreads();
    }

    float ncol[4];
#pragma unroll
    for (int n = 0; n < 4; n++) ncol[n] = nrm[tc0 + wn * 64 + n * 16 + q];
#pragma unroll
    for (int m = 0; m < 4; m++)
#pragma unroll
        for (int j = 0; j < 4; j++) {
            int row = wm * 64 + m * 16 + g * 4 + j;
            float thr8 = 8.0f * nrm[tr0 + row];
#pragma unroll
            for (int n = 0; n < 4; n++) {
                int col = wn * 64 + n * 16 + q;
                tmat[row * 132 + col] = (acc[m][n][j] >= thr8 * ncol[n]) ? 1 : 0;
            }
        }
    __syncthreads();

    for (int rr = 0; rr < 32; rr++) {
        int row = w * 32 + rr;
#pragma unroll
        for (int h = 0; h < 2; h++) {
            u64 b = __ballot(tmat[row * 132 + h * 64 + lane] != 0);
            if (lane < 2)
                bits[(size_t)(tr0 + row) * NWRD + bj * 4 + 2 * h + lane] = (u32)(b >> (32 * lane));
        }
    }
    if (bi != bj) {
        for (int rr = 0; rr < 32; rr++) {
            int c = w * 32 + rr;
#pragma unroll
            for (int h = 0; h < 2; h++) {
                u64 b = __ballot(tmat[(h * 64 + lane) * 132 + c] != 0);
                if (lane < 2)
                    bits[(size_t)(tc0 + c) * NWRD + bi * 4 + 2 * h + lane] = (u32)(b >> (32 * lane));
            }
        }
    }
}

// ---------------------------------------------------------------- iou_bits
__global__ __launch_bounds__(256) void iou_bits(const float* __restrict__ boxes,
                                                u32* __restrict__ bits) {
    __shared__ float bx[N_BOX * 4];
    int blk = blockIdx.x;
    int img = blk / 500;
    int r0 = (blk % 500) * 4;
    const float* bb = boxes + (size_t)img * N_BOX * 4;
    for (int i = threadIdx.x; i < N_BOX * 4; i += 256) bx[i] = bb[i];
    __syncthreads();
    int t = threadIdx.x;
    int ri = r0 + (t >> 6);
    int wi = t & 63;
    float x1a = bx[ri * 4 + 0], y1a = bx[ri * 4 + 1];
    float x2a = bx[ri * 4 + 2], y2a = bx[ri * 4 + 3];
    float areaA = __fmul_rn(__fsub_rn(x2a, x1a), __fsub_rn(y2a, y1a));
    u32 wv = 0;
    int jb = wi * 32;
#pragma unroll 4
    for (int s = 0; s < 32; s++) {
        int j = jb + s;
        if (j < N_BOX) {
            float x1b = bx[j * 4 + 0], y1b = bx[j * 4 + 1];
            float x2b = bx[j * 4 + 2], y2b = bx[j * 4 + 3];
            float areaB = __fmul_rn(__fsub_rn(x2b, x1b), __fsub_rn(y2b, y1b));
            float ltx = fmaxf(x1a, x1b), lty = fmaxf(y1a, y1b);
            float rbx = fminf(x2a, x2b), rby = fminf(y2a, y2b);
            float wx = fmaxf(__fsub_rn(rbx, ltx), 0.0f);
            float wy = fmaxf(__fsub_rn(rby, lty), 0.0f);
            float inter = __fmul_rn(wx, wy);
            float uni = __fsub_rn(__fadd_rn(areaA, areaB), inter);
            float iou = __fdiv_rn(inter, fmaxf(uni, 1e-12f));
            if (iou >= 0.5f) wv |= (1u << s);
        }
    }
    bits[((size_t)img * N_PAD + ri) * NWRD + wi] = wv;
}

// ---------------------------------------------------------------- ygemm_part
// K-split x4: grid (1000, 4), 1 wave/block, 32 steps/wave. Barrier-free,
// LDS-free per-lane fragment loads; emits SF fp8 + partial sums + partial Y.
#define YG_LOADW(ks, WH_, WL_)                                                \
    _Pragma("unroll")                                                         \
    for (int n = 0; n < 6; n++) {                                             \
        int col = n * 16 + q;                                                 \
        WH_[n] = *(const s16x8*)(Wh + (size_t)col * C_DIM + (ks) + g * 8);    \
        WL_[n] = *(const s16x8*)(Wl + (size_t)col * C_DIM + (ks) + g * 8);    \
    }

#define YG_STEP(sidx, d, CH, CL, NH, NL)                                      \
    {                                                                         \
        int s_ = (sidx);                                                      \
        if (s_ + 1 < YG_LSTEPS) { YG_LOADW(ks0 + (s_ + 1) * 32, NH, NL) }     \
        float4 a0 = xa[d][0], a1 = xa[d][1];                                  \
        if (s_ + 4 < YG_LSTEPS) {                                             \
            xa[d][0] = *(const float4*)(xp + (s_ + 4) * 32);                  \
            xa[d][1] = *(const float4*)(xp + (s_ + 4) * 32 + 4);              \
        }                                                                     \
        float e[8] = {a0.x, a0.y, a0.z, a0.w, a1.x, a1.y, a1.z, a1.w};        \
        if (emit) {                                                           \
            sum += e[0] + e[1] + e[2] + e[3] + e[4] + e[5] + e[6] + e[7];     \
            ssq += e[0]*e[0] + e[1]*e[1] + e[2]*e[2] + e[3]*e[3] +            \
                   e[4]*e[4] + e[5]*e[5] + e[6]*e[6] + e[7]*e[7];             \
            u32 lo = __builtin_amdgcn_cvt_pk_fp8_f32(4.f*e[0], 4.f*e[1], 0, false); \
            lo = __builtin_amdgcn_cvt_pk_fp8_f32(4.f*e[2], 4.f*e[3], lo, true);     \
            u32 hi = __builtin_amdgcn_cvt_pk_fp8_f32(4.f*e[4], 4.f*e[5], 0, false); \
            hi = __builtin_amdgcn_cvt_pk_fp8_f32(4.f*e[6], 4.f*e[7], hi, true);     \
            *(uint2*)(sfp + (size_t)s_ * 32) = make_uint2(lo, hi);            \
        }                                                                     \
        s16x8 fah, fal;                                                       \
        _Pragma("unroll")                                                     \
        for (int j2 = 0; j2 < 8; j2++) {                                      \
            u32 hb = f2bf(e[j2]);                                             \
            float hf = __uint_as_float(hb << 16);                             \
            fah[j2] = (short)hb;                                              \
            fal[j2] = (short)f2bf(e[j2] - hf);                                \
        }                                                                     \
        _Pragma("unroll")                                                     \
        for (int n = 0; n < 6; n++) {                                         \
            acc[n] = __builtin_amdgcn_mfma_f32_16x16x32_bf16(fah, CH[n], acc[n], 0, 0, 0); \
            acc[n] = __builtin_amdgcn_mfma_f32_16x16x32_bf16(fal, CH[n], acc[n], 0, 0, 0); \
            acc[n] = __builtin_amdgcn_mfma_f32_16x16x32_bf16(fah, CL[n], acc[n], 0, 0, 0); \
        }                                                                     \
    }

__global__ __launch_bounds__(64) void ygemm_part(const float* __restrict__ x,
                                                 const u16* __restrict__ Wh,
                                                 const u16* __restrict__ Wl,
                                                 u8* __restrict__ SF,
                                                 float* __restrict__ PS,
                                                 float* __restrict__ PQ,
                                                 float* __restrict__ P,
                                                 int emit) {
    int lane = threadIdx.x;
    int q = lane & 15, g = lane >> 4;
    int row0 = blockIdx.x * 16;           // 16 rows per wave; 2000%16==0
    int kz = blockIdx.y;
    int ks0 = kz * (C_DIM / KSPLIT);
    int grow = row0 + q;
    int img = grow / N_BOX, nrow = grow - img * N_BOX;
    const float* xp = x + (size_t)grow * C_DIM + ks0 + g * 8;
    u8* sfp = SF + ((size_t)img * N_PAD + nrow) * C_DIM + ks0 + g * 8;

    f32x4 acc[6] = {};
    float sum = 0.0f, ssq = 0.0f;

    float4 xa[4][2];
#pragma unroll
    for (int d = 0; d < 4; d++) {
        xa[d][0] = *(const float4*)(xp + d * 32);
        xa[d][1] = *(const float4*)(xp + d * 32 + 4);
    }
    s16x8 wAh[6], wAl[6], wBh[6], wBl[6];
    YG_LOADW(ks0, wAh, wAl)

#pragma unroll 1
    for (int so = 0; so < YG_LSTEPS / 4; ++so) {
        YG_STEP(so * 4 + 0, 0, wAh, wAl, wBh, wBl)
        YG_STEP(so * 4 + 1, 1, wBh, wBl, wAh, wAl)
        YG_STEP(so * 4 + 2, 2, wAh, wAl, wBh, wBl)
        YG_STEP(so * 4 + 3, 3, wBh, wBl, wAh, wAl)
    }

    if (emit) {
        sum += __shfl_xor(sum, 16); sum += __shfl_xor(sum, 32);
        ssq += __shfl_xor(ssq, 16); ssq += __shfl_xor(ssq, 32);
        if (g == 0) {
            PS[kz * 16000 + grow] = sum;
            PQ[kz * 16000 + grow] = ssq;
        }
    }
    float* Pk = P + (size_t)kz * 16000 * 96;
#pragma unroll
    for (int j = 0; j < 4; j++)
#pragma unroll
        for (int n = 0; n < 6; n++)
            Pk[(size_t)(row0 + g * 4 + j) * 96 + n * 16 + q] = acc[n][j];
}

// ---------------------------------------------------------------- ygemm_stats
__global__ __launch_bounds__(256) void ygemm_stats(const float* __restrict__ PS,
                                                   const float* __restrict__ PQ,
                                                   float* __restrict__ INV,
                                                   float* __restrict__ NRM) {
    int r = blockIdx.x * 256 + threadIdx.x;
    if (r >= 16000) return;
    float s = PS[r] + PS[16000 + r] + PS[32000 + r] + PS[48000 + r];
    float qq = PQ[r] + PQ[16000 + r] + PQ[32000 + r] + PQ[48000 + r];
    INV[r] = (s == 0.0f) ? 0.0f : 1.0f / s;
    int img = r / N_BOX, n = r - img * N_BOX;
    NRM[(size_t)img * N_PAD + n] = sqrtf(qq);
}

// ---------------------------------------------------------------- ygemm_reduce
__global__ __launch_bounds__(256) void ygemm_reduce(const float* __restrict__ P,
                                                    const float* __restrict__ INV,
                                                    float* __restrict__ Y) {
    int gid = blockIdx.x * 256 + threadIdx.x;
    if (gid >= 16000 * 96) return;
    float s = P[gid] + P[gid + 1536000] + P[gid + 2 * 1536000] + P[gid + 3 * 1536000];
    Y[gid] = s * INV[gid / 96];
}

// ---------------------------------------------------------------- spmm1
__global__ __launch_bounds__(256) void spmm1(const u32* __restrict__ Aadj,
                                             const u32* __restrict__ Asim,
                                             const float* __restrict__ Y,
                                             const float* __restrict__ bc1,
                                             const float* __restrict__ bd1,
                                             float* __restrict__ H) {
    int gw = blockIdx.x * 4 + (threadIdx.x >> 6);
    int lane = threadIdx.x & 63;
    if (lane >= HIDN) return;
    int i = gw >> 1, br = gw & 1;
    int img = i / N_BOX, n = i % N_BOX;
    const u32* bp = (br ? Asim : Aadj) + ((size_t)img * N_PAD + n) * NWRD;
    const float* Yb = Y + (size_t)img * N_BOX * 96 + br * HIDN + lane;
    float acc = 0.0f;
    for (int w8 = 0; w8 < NWRD; w8++) {
        u32 wv = bp[w8];
        while (wv) {
            int s = __builtin_ctz(wv);
            wv &= wv - 1;
            acc += Yb[(size_t)(w8 * 32 + s) * 96];
        }
    }
    float bias = br ? bd1[lane] : bc1[lane];
    H[(size_t)i * 96 + br * HIDN + lane] = fmaxf(acc + bias, 0.0f);
}

// ---------------------------------------------------------------- gemm2
__global__ __launch_bounds__(256) void gemm2(const float* __restrict__ H,
                                             const float* __restrict__ Wc2,
                                             const float* __restrict__ Wd2,
                                             float* __restrict__ Z) {
    __shared__ float w2[2 * HIDN * NCLS];
    for (int idx = threadIdx.x; idx < 2 * HIDN * NCLS; idx += 256) {
        int br = idx / (HIDN * NCLS), e = idx % (HIDN * NCLS);
        w2[idx] = br ? Wd2[e] : Wc2[e];
    }
    __syncthreads();
    int gidx = blockIdx.x * 256 + threadIdx.x;
    if (gidx >= 16000 * 40) return;
    int i = gidx / 40, rem = gidx % 40;
    int br = rem / NCLS, c2 = rem % NCLS;
    const float* hrow = H + (size_t)i * 96 + br * HIDN;
    const float* wp = w2 + br * HIDN * NCLS;
    float acc = 0.0f;
#pragma unroll
    for (int h = 0; h < HIDN; h++) acc += hrow[h] * wp[h * NCLS + c2];
    Z[gidx] = acc;
}

// ---------------------------------------------------------------- spmm2 -> logits
__global__ __launch_bounds__(256) void spmm2(const u32* __restrict__ Aadj,
                                             const u32* __restrict__ Asim,
                                             const float* __restrict__ Z,
                                             const float* __restrict__ bc2,
                                             const float* __restrict__ bd2,
                                             float* __restrict__ out) {
    int gw = blockIdx.x * 4 + (threadIdx.x >> 6);
    int lane = threadIdx.x & 63;
    if (lane >= NCLS) return;
    int i = gw >> 1, br = gw & 1;
    int img = i / N_BOX, n = i % N_BOX;
    const u32* bp = (br ? Asim : Aadj) + ((size_t)img * N_PAD + n) * NWRD;
    const float* Zb = Z + (size_t)img * N_BOX * 40 + br * NCLS + lane;
    float acc = 0.0f;
    for (int w8 = 0; w8 < NWRD; w8++) {
        u32 wv = bp[w8];
        while (wv) {
            int s = __builtin_ctz(wv);
            wv &= wv - 1;
            acc += Zb[(size_t)(w8 * 32 + s) * 40];
        }
    }
    float logit = acc + (br ? bd2[lane] : bc2[lane]);
    out[(br ? 320000 : 0) + (size_t)i * NCLS + lane] = logit;
}

// ---------------------------------------------------------------- softmaxes
__global__ __launch_bounds__(256) void softmax_cls(float* __restrict__ out) {
    int i = blockIdx.x * 256 + threadIdx.x;
    if (i >= 16000) return;
    float* p = out + (size_t)i * NCLS;
    float m = p[0];
#pragma unroll
    for (int c = 1; c < NCLS; c++) m = fmaxf(m, p[c]);
    float e[NCLS], s = 0.0f;
#pragma unroll
    for (int c = 0; c < NCLS; c++) { e[c] = expf(p[c] - m); s += e[c]; }
    float inv = 1.0f / s;
#pragma unroll
    for (int c = 0; c < NCLS; c++) p[c] = e[c] * inv;
}

__global__ __launch_bounds__(256) void softmax_det(float* __restrict__ out) {
    __shared__ float vals[N_BOX];
    __shared__ float redm[4];
    __shared__ float reds[4];
    int img = blockIdx.x / NCLS, c = blockIdx.x % NCLS;
    float* base = out + 320000 + (size_t)img * N_BOX * NCLS + c;
    int t = threadIdx.x;
    float m = -3.4e38f;
    for (int n = t; n < N_BOX; n += 256) {
        float v = base[(size_t)n * NCLS];
        vals[n] = v;
        m = fmaxf(m, v);
    }
#pragma unroll
    for (int off = 32; off; off >>= 1) m = fmaxf(m, __shfl_down(m, off));
    if ((t & 63) == 0) redm[t >> 6] = m;
    __syncthreads();
    m = fmaxf(fmaxf(redm[0], redm[1]), fmaxf(redm[2], redm[3]));
    float s = 0.0f;
    for (int n = t; n < N_BOX; n += 256) s += expf(vals[n] - m);
#pragma unroll
    for (int off = 32; off; off >>= 1) s += __shfl_down(s, off);
    if ((t & 63) == 0) reds[t >> 6] = s;
    __syncthreads();
    s = reds[0] + reds[1] + reds[2] + reds[3];
    float inv = 1.0f / s;
    for (int n = t; n < N_BOX; n += 256) base[(size_t)n * NCLS] = expf(vals[n] - m) * inv;
}

// ---------------------------------------------------------------- launch
extern "C" void kernel_launch(void* const* d_in, const int* in_sizes, int n_in,
                              void* d_out, int out_size, void* d_ws, size_t ws_size,
                              hipStream_t stream) {
    const float* x1    = (const float*)d_in[0];
    const float* boxes = (const float*)d_in[2];
    const float* W_cls1 = (const float*)d_in[3];
    const float* b_cls1 = (const float*)d_in[4];
    const float* W_cls2 = (const float*)d_in[5];
    const float* b_cls2 = (const float*)d_in[6];
    const float* W_det1 = (const float*)d_in[7];
    const float* b_det1 = (const float*)d_in[8];
    const float* W_det2 = (const float*)d_in[9];
    const float* b_det2 = (const float*)d_in[10];
    float* out = (float*)d_out;

    char* ws = (char*)d_ws;
    size_t off = 0;
    auto alloc = [&](size_t bytes) -> void* {
        void* p = ws + off;
        off = (off + bytes + 255) & ~(size_t)255;
        return p;
    };
    u16* WTH   = (u16*)alloc((size_t)96 * C_DIM * 2);
    u16* WTL   = (u16*)alloc((size_t)96 * C_DIM * 2);
    float* INV = (float*)alloc((size_t)16000 * 4);
    float* NRM = (float*)alloc((size_t)B_IMG * N_PAD * 4);
    float* PS  = (float*)alloc((size_t)KSPLIT * 16000 * 4);
    float* PQ  = (float*)alloc((size_t)KSPLIT * 16000 * 4);
    u32* AADJ  = (u32*)alloc((size_t)B_IMG * N_PAD * NWRD * 4);
    u32* ASIM  = (u32*)alloc((size_t)B_IMG * N_PAD * NWRD * 4);
    float* Y   = (float*)alloc((size_t)16000 * 96 * 4);
    float* H   = (float*)alloc((size_t)16000 * 96 * 4);
    float* Z   = (float*)alloc((size_t)16000 * 40 * 4);
    float* P   = (float*)alloc((size_t)KSPLIT * 16000 * 96 * 4);
    size_t base_need = off;
    size_t sf_full = (size_t)B_IMG * N_PAD * C_DIM;   // fp8: 1 B/elem
    bool full = (ws_size >= base_need + sf_full);
    u8* SF = (u8*)alloc(full ? sf_full : (size_t)N_PAD * C_DIM);

    wt_build<<<dim3(1536), dim3(256), 0, stream>>>(W_cls1, W_det1, WTH, WTL);
    iou_bits<<<dim3(B_IMG * 500), dim3(256), 0, stream>>>(boxes, AADJ);

    if (full) {
        sf_pad<<<dim3(B_IMG * 48), dim3(256), 0, stream>>>(SF, NRM);
        ygemm_part<<<dim3(1000, KSPLIT), dim3(64), 0, stream>>>(
            x1, WTH, WTL, SF, PS, PQ, P, 1);
        ygemm_stats<<<dim3(63), dim3(256), 0, stream>>>(PS, PQ, INV, NRM);
        gemm_sim<<<dim3(NPAIR, 1, B_IMG), dim3(256), 0, stream>>>(SF, NRM, ASIM);
        ygemm_reduce<<<dim3(6000), dim3(256), 0, stream>>>(P, INV, Y);
    } else {
        for (int b = 0; b < B_IMG; b++) {
            rowstats<<<dim3(N_PAD), dim3(256), 0, stream>>>(
                x1 + (size_t)b * N_BOX * C_DIM, INV + (size_t)b * N_BOX, SF,
                NRM + (size_t)b * N_PAD);
            gemm_sim<<<dim3(NPAIR, 1, 1), dim3(256), 0, stream>>>(
                SF, NRM + (size_t)b * N_PAD, ASIM + (size_t)b * N_PAD * NWRD);
        }
        ygemm_part<<<dim3(1000, KSPLIT), dim3(64), 0, stream>>>(
            x1, WTH, WTL, SF, PS, PQ, P, 0);
        ygemm_reduce<<<dim3(6000), dim3(256), 0, stream>>>(P, INV, Y);
    }

    spmm1<<<dim3(8000), dim3(256), 0, stream>>>(AADJ, ASIM, Y, b_cls1, b_det1, H);
    gemm2<<<dim3(2500), dim3(256), 0, stream>>>(H, W_cls2, W_det2, Z);
    spmm2<<<dim3(8000), dim3(256), 0, stream>>>(AADJ, ASIM, Z, b_cls2, b_det2, out);
    softmax_cls<<<dim3(63), dim3(256), 0, stream>>>(out);
    softmax_det<<<dim3(160), dim3(256), 0, stream>>>(out);
    (void)in_sizes; (void)n_in; (void)out_size; (void)d_in; (void)ws_size;
}

// Round 11
// 469.907 us; speedup vs baseline: 1.2657x; 1.2657x over previous
//
#include <hip/hip_runtime.h>
#include <stdint.h>

typedef unsigned int u32;
typedef unsigned long long u64;
typedef unsigned short u16;
typedef unsigned char u8;

#define B_IMG 8
#define N_BOX 2000
#define N_PAD 2048
#define C_DIM 4096
#define HIDN 42
#define NCLS 20
#define NWRD 64   // 2048 bits per adjacency row
#define NPAIR 136 // 16*17/2 lower-triangle 128-tiles
#define KSPLIT 2
#define YG_NS 64   // (4096/KSPLIT)/32 steps per block

using f32x4 = __attribute__((ext_vector_type(4))) float;
using s16x8 = __attribute__((ext_vector_type(8))) short;

__device__ __forceinline__ u32 f2bf(float f) {   // fp32 -> bf16 RNE
    u32 u = __float_as_uint(f);
    u += 0x7FFFu + ((u >> 16) & 1u);
    return u >> 16;
}

#define GLOAD_LDS16(g, l)                                                     \
    __builtin_amdgcn_global_load_lds(                                         \
        (const __attribute__((address_space(1))) void*)(g),                   \
        (__attribute__((address_space(3))) void*)(l), 16, 0, 0)

// ---------------------------------------------------------------- wt_build
__global__ __launch_bounds__(256) void wt_build(const float* __restrict__ Wc,
                                                const float* __restrict__ Wd,
                                                u16* __restrict__ Wth,
                                                u16* __restrict__ Wtl) {
    int g = blockIdx.x * 256 + threadIdx.x;
    if (g >= 96 * C_DIM) return;
    int k = g & (C_DIM - 1);
    int c = g >> 12;
    float v = 0.0f;
    if (c < HIDN) v = Wc[k * HIDN + c];
    else if (c < 2 * HIDN) v = Wd[k * HIDN + (c - HIDN)];
    u32 hb = f2bf(v);
    float hf = __uint_as_float(hb << 16);
    u32 lb = f2bf(v - hf);
    Wth[g] = (u16)hb;
    Wtl[g] = (u16)lb;
}

// ---------------------------------------------------------------- sf_pad
__global__ __launch_bounds__(256) void sf_pad(u8* __restrict__ SF,
                                              float* __restrict__ NRM) {
    int row = blockIdx.x;                  // 0..383
    int img = row / 48, n = N_BOX + row % 48;
    uint4* p = (uint4*)(SF + ((size_t)img * N_PAD + n) * C_DIM);
    uint4 z = make_uint4(0, 0, 0, 0);
    p[threadIdx.x] = z;                    // 256 x 16B = 4096 B
    if (threadIdx.x == 0) NRM[(size_t)img * N_PAD + n] = 1e9f;
}

// ---------------------------------------------------------------- rowstats (fallback only)
__global__ __launch_bounds__(256) void rowstats(const float* __restrict__ x,
                                                float* __restrict__ inv_sum,
                                                u8* __restrict__ sf,
                                                float* __restrict__ nrm) {
    int r = blockIdx.x;
    int t = threadIdx.x;
    u8* sfrow = sf + (size_t)r * C_DIM;
    if (r >= N_BOX) {
        uint4 z = make_uint4(0, 0, 0, 0);
        uint4* p = (uint4*)sfrow;
        for (int i = t; i < C_DIM / 16; i += 256) p[i] = z;
        if (t == 0) nrm[r] = 1e9f;
        return;
    }
    const float4* xr = (const float4*)(x + (size_t)r * C_DIM);
    float4 v[4];
    float s = 0.0f, ss = 0.0f;
#pragma unroll
    for (int i = 0; i < 4; i++) {
        v[i] = xr[t + 256 * i];
        s += v[i].x + v[i].y + v[i].z + v[i].w;
        ss += v[i].x * v[i].x + v[i].y * v[i].y + v[i].z * v[i].z + v[i].w * v[i].w;
    }
    __shared__ float red[4][2];
#pragma unroll
    for (int off = 32; off; off >>= 1) {
        s += __shfl_down(s, off);
        ss += __shfl_down(ss, off);
    }
    int wid = t >> 6, lane = t & 63;
    if (lane == 0) { red[wid][0] = s; red[wid][1] = ss; }
    __syncthreads();
    s  = red[0][0] + red[1][0] + red[2][0] + red[3][0];
    ss = red[0][1] + red[1][1] + red[2][1] + red[3][1];
    if (t == 0) {
        inv_sum[r] = (s == 0.0f) ? 0.0f : 1.0f / s;
        nrm[r] = sqrtf(ss);
    }
    u32* sp = (u32*)sfrow;
#pragma unroll
    for (int i = 0; i < 4; i++) {
        float4 w = v[i];
        u32 pk = __builtin_amdgcn_cvt_pk_fp8_f32(4.f * w.x, 4.f * w.y, 0, false);
        pk = __builtin_amdgcn_cvt_pk_fp8_f32(4.f * w.z, 4.f * w.w, pk, true);
        sp[t + 256 * i] = pk;
    }
}

// ---------------------------------------------------------------- gemm_sim
__global__ __launch_bounds__(256) void gemm_sim(const u8* __restrict__ sf_all,
                                                const float* __restrict__ nrm_all,
                                                u32* __restrict__ bits_all) {
    __shared__ __align__(16) char smem[32768];   // [A0 8K][B0 8K][A1 8K][B1 8K]
    char* tmat = smem;                           // epilogue reuse [128][132]

    int z = blockIdx.z;
    const u8* sf = sf_all + (size_t)z * N_PAD * C_DIM;
    const float* nrm = nrm_all + (size_t)z * N_PAD;
    u32* bits = bits_all + (size_t)z * N_PAD * NWRD;

    int p = blockIdx.x;
    int bi = (int)((sqrtf(8.0f * p + 1.0f) - 1.0f) * 0.5f);
    while (bi * (bi + 1) / 2 > p) bi--;
    while ((bi + 1) * (bi + 2) / 2 <= p) bi++;
    int bj = p - bi * (bi + 1) / 2;

    int t = threadIdx.x;
    int lane = t & 63;
    int w = t >> 6;
    int wm = w >> 1, wn = w & 1;
    int tr0 = bi * 128, tc0 = bj * 128;
    f32x4 acc[4][4] = {};
    int q = lane & 15, g = lane >> 4;
    int swz = (q >> 1) & 3;
    int g8 = (g & 1) * 8, gh = g >> 1;

    auto stage = [&](int it, int b) {
        int k0 = it * 64;
        u8* As = (u8*)smem + b * 16384;
        u8* Bs = As + 8192;
#pragma unroll
        for (int i = 0; i < 2; i++) {
            int ci = t + 256 * i;            // 0..511 16B-chunks
            int r = ci >> 2, c16 = ci & 3;
            int sc16 = c16 ^ ((r >> 1) & 3);
            GLOAD_LDS16(sf + ((size_t)(tr0 + r) << 12) + k0 + sc16 * 16,
                        As + ci * 16);
            GLOAD_LDS16(sf + ((size_t)(tc0 + r) << 12) + k0 + sc16 * 16,
                        Bs + ci * 16);
        }
    };

    stage(0, 0);
    __syncthreads();
    for (int it = 0; it < 64; ++it) {
        int cur = it & 1;
        if (it + 1 < 64) stage(it + 1, cur ^ 1);   // prefetch under MFMA
        const u8* As = (const u8*)smem + cur * 16384;
        const u8* Bs = As + 8192;
#pragma unroll
        for (int kk = 0; kk < 2; kk++) {
            int boff = ((2 * kk + gh) ^ swz) * 16 + g8;
            long long a[4], b[4];
#pragma unroll
            for (int m = 0; m < 4; m++)
                a[m] = *(const long long*)(As + (wm * 64 + m * 16 + q) * 64 + boff);
#pragma unroll
            for (int n = 0; n < 4; n++)
                b[n] = *(const long long*)(Bs + (wn * 64 + n * 16 + q) * 64 + boff);
#pragma unroll
            for (int m = 0; m < 4; m++)
#pragma unroll
                for (int n = 0; n < 4; n++)
                    acc[m][n] = __builtin_amdgcn_mfma_f32_16x16x32_fp8_fp8(a[m], b[n], acc[m][n], 0, 0, 0);
        }
        __syncthreads();
    }

    float ncol[4];
#pragma unroll
    for (int n = 0; n < 4; n++) ncol[n] = nrm[tc0 + wn * 64 + n * 16 + q];
#pragma unroll
    for (int m = 0; m < 4; m++)
#pragma unroll
        for (int j = 0; j < 4; j++) {
            int row = wm * 64 + m * 16 + g * 4 + j;
            float thr8 = 8.0f * nrm[tr0 + row];
#pragma unroll
            for (int n = 0; n < 4; n++) {
                int col = wn * 64 + n * 16 + q;
                tmat[row * 132 + col] = (acc[m][n][j] >= thr8 * ncol[n]) ? 1 : 0;
            }
        }
    __syncthreads();

    for (int rr = 0; rr < 32; rr++) {
        int row = w * 32 + rr;
#pragma unroll
        for (int h = 0; h < 2; h++) {
            u64 b = __ballot(tmat[row * 132 + h * 64 + lane] != 0);
            if (lane < 2)
                bits[(size_t)(tr0 + row) * NWRD + bj * 4 + 2 * h + lane] = (u32)(b >> (32 * lane));
        }
    }
    if (bi != bj) {
        for (int rr = 0; rr < 32; rr++) {
            int c = w * 32 + rr;
#pragma unroll
            for (int h = 0; h < 2; h++) {
                u64 b = __ballot(tmat[(h * 64 + lane) * 132 + c] != 0);
                if (lane < 2)
                    bits[(size_t)(tc0 + c) * NWRD + bi * 4 + 2 * h + lane] = (u32)(b >> (32 * lane));
            }
        }
    }
}

// ---------------------------------------------------------------- iou_bits
__global__ __launch_bounds__(256) void iou_bits(const float* __restrict__ boxes,
                                                u32* __restrict__ bits) {
    __shared__ float bx[N_BOX * 4];
    int blk = blockIdx.x;
    int img = blk / 500;
    int r0 = (blk % 500) * 4;
    const float* bb = boxes + (size_t)img * N_BOX * 4;
    for (int i = threadIdx.x; i < N_BOX * 4; i += 256) bx[i] = bb[i];
    __syncthreads();
    int t = threadIdx.x;
    int ri = r0 + (t >> 6);
    int wi = t & 63;
    float x1a = bx[ri * 4 + 0], y1a = bx[ri * 4 + 1];
    float x2a = bx[ri * 4 + 2], y2a = bx[ri * 4 + 3];
    float areaA = __fmul_rn(__fsub_rn(x2a, x1a), __fsub_rn(y2a, y1a));
    u32 wv = 0;
    int jb = wi * 32;
#pragma unroll 4
    for (int s = 0; s < 32; s++) {
        int j = jb + s;
        if (j < N_BOX) {
            float x1b = bx[j * 4 + 0], y1b = bx[j * 4 + 1];
            float x2b = bx[j * 4 + 2], y2b = bx[j * 4 + 3];
            float areaB = __fmul_rn(__fsub_rn(x2b, x1b), __fsub_rn(y2b, y1b));
            float ltx = fmaxf(x1a, x1b), lty = fmaxf(y1a, y1b);
            float rbx = fminf(x2a, x2b), rby = fminf(y2a, y2b);
            float wx = fmaxf(__fsub_rn(rbx, ltx), 0.0f);
            float wy = fmaxf(__fsub_rn(rby, lty), 0.0f);
            float inter = __fmul_rn(wx, wy);
            float uni = __fsub_rn(__fadd_rn(areaA, areaB), inter);
            float iou = __fdiv_rn(inter, fmaxf(uni, 1e-12f));
            if (iou >= 0.5f) wv |= (1u << s);
        }
    }
    bits[((size_t)img * N_PAD + ri) * NWRD + wi] = wv;
}

// ---------------------------------------------------------------- ygemm_part
// r7 LDS structure + depth-4 x register prefetch + K-split x2.
// grid (250, 2), 256 threads, BM=64, BN=96, 64 steps of BK=32 per block.
// Emits SF fp8 + partial sum/ssq + partial (unscaled) Y.
#define YG_STEP(s_, d, bufc)                                                  \
    {                                                                         \
        float4 a0 = pa[d][0], a1 = pa[d][1];                                  \
        float e[8] = {a0.x, a0.y, a0.z, a0.w, a1.x, a1.y, a1.z, a1.w};        \
        if (emit) {                                                           \
            sum += e[0] + e[1] + e[2] + e[3] + e[4] + e[5] + e[6] + e[7];     \
            ssq += e[0]*e[0] + e[1]*e[1] + e[2]*e[2] + e[3]*e[3] +            \
                   e[4]*e[4] + e[5]*e[5] + e[6]*e[6] + e[7]*e[7];             \
            u32 lo = __builtin_amdgcn_cvt_pk_fp8_f32(4.f*e[0], 4.f*e[1], 0, false); \
            lo = __builtin_amdgcn_cvt_pk_fp8_f32(4.f*e[2], 4.f*e[3], lo, true);     \
            u32 hi = __builtin_amdgcn_cvt_pk_fp8_f32(4.f*e[4], 4.f*e[5], 0, false); \
            hi = __builtin_amdgcn_cvt_pk_fp8_f32(4.f*e[6], 4.f*e[7], hi, true);     \
            *(uint2*)(sfp + (size_t)(s_) * 32) = make_uint2(lo, hi);          \
        }                                                                     \
        u32 hb[8], lb[8];                                                     \
        _Pragma("unroll")                                                     \
        for (int j2 = 0; j2 < 8; j2++) {                                      \
            hb[j2] = f2bf(e[j2]);                                             \
            float hf = __uint_as_float(hb[j2] << 16);                         \
            lb[j2] = f2bf(e[j2] - hf);                                        \
        }                                                                     \
        *(uint4*)&Ah[bufc][t * 8] = make_uint4(hb[0]|(hb[1]<<16), hb[2]|(hb[3]<<16), \
                                               hb[4]|(hb[5]<<16), hb[6]|(hb[7]<<16)); \
        *(uint4*)&Al[bufc][t * 8] = make_uint4(lb[0]|(lb[1]<<16), lb[2]|(lb[3]<<16), \
                                               lb[4]|(lb[5]<<16), lb[6]|(lb[7]<<16)); \
        __syncthreads();                                                      \
        if ((s_) + 1 < YG_NS) stage_B((s_) + 1, (bufc) ^ 1);                  \
        if ((s_) + 4 < YG_NS) {                                               \
            pa[d][0] = *(const float4*)(xrow + ((s_) + 4) * 32);              \
            pa[d][1] = *(const float4*)(xrow + ((s_) + 4) * 32 + 4);          \
        }                                                                     \
        s16x8 fah[2], fal[2], fbh[3], fbl[3];                                 \
        _Pragma("unroll")                                                     \
        for (int m = 0; m < 2; m++) {                                         \
            fah[m] = *(const s16x8*)&Ah[bufc][(wr + m * 16 + q) * 32 + g * 8]; \
            fal[m] = *(const s16x8*)&Al[bufc][(wr + m * 16 + q) * 32 + g * 8]; \
        }                                                                     \
        _Pragma("unroll")                                                     \
        for (int n = 0; n < 3; n++) {                                         \
            fbh[n] = *(const s16x8*)&Bh[bufc][(wc + n * 16 + q) * 32 + g * 8]; \
            fbl[n] = *(const s16x8*)&Bl[bufc][(wc + n * 16 + q) * 32 + g * 8]; \
        }                                                                     \
        _Pragma("unroll")                                                     \
        for (int m = 0; m < 2; m++)                                           \
            _Pragma("unroll")                                                 \
            for (int n = 0; n < 3; n++) {                                     \
                acc[m][n] = __builtin_amdgcn_mfma_f32_16x16x32_bf16(fah[m], fbh[n], acc[m][n], 0, 0, 0); \
                acc[m][n] = __builtin_amdgcn_mfma_f32_16x16x32_bf16(fal[m], fbh[n], acc[m][n], 0, 0, 0); \
                acc[m][n] = __builtin_amdgcn_mfma_f32_16x16x32_bf16(fah[m], fbl[n], acc[m][n], 0, 0, 0); \
            }                                                                 \
    }

__global__ __launch_bounds__(256) void ygemm_part(const float* __restrict__ x,
                                                  const u16* __restrict__ Wh,
                                                  const u16* __restrict__ Wl,
                                                  u8* __restrict__ SF,
                                                  float* __restrict__ PS,
                                                  float* __restrict__ PQ,
                                                  float* __restrict__ P,
                                                  int emit) {
    __shared__ u16 Ah[2][64 * 32];
    __shared__ u16 Al[2][64 * 32];
    __shared__ u16 Bh[2][96 * 32];
    __shared__ u16 Bl[2][96 * 32];

    int t = threadIdx.x;
    int row0 = blockIdx.x * 64;
    int kz = blockIdx.y;
    int ks0 = kz * (C_DIM / KSPLIT);
    int ar = t >> 2;                       // staging row 0..63
    int grow = row0 + ar;
    int img = grow / N_BOX, nrow = grow - img * N_BOX;
    const float* xrow = x + (size_t)grow * C_DIM + ks0 + (t & 3) * 8;
    u8* sfp = SF + ((size_t)img * N_PAD + nrow) * C_DIM + ks0 + (t & 3) * 8;

    int w = t >> 6, lane = t & 63;
    int q = lane & 15, g = lane >> 4;
    int wr = (w & 1) * 32, wc = (w >> 1) * 48;

    f32x4 acc[2][3] = {};
    float sum = 0.0f, ssq = 0.0f;

    auto stage_B = [&](int sstep, int b) {
        int ks = ks0 + sstep * 32;
#pragma unroll
        for (int i = 0; i < 3; i++) {
            int idx = t + 256 * i;
            int half = idx >= 384;
            int loc = half ? idx - 384 : idx;
            int cr = loc >> 2, kc2 = loc & 3;
            const u16* src = (half ? Wl : Wh) + (size_t)cr * C_DIM + ks + kc2 * 8;
            u16* dst = (half ? Bl[b] : Bh[b]) + loc * 8;
            GLOAD_LDS16(src, dst);
        }
    };

    float4 pa[4][2];
#pragma unroll
    for (int d = 0; d < 4; d++) {
        pa[d][0] = *(const float4*)(xrow + d * 32);
        pa[d][1] = *(const float4*)(xrow + d * 32 + 4);
    }
    stage_B(0, 0);

#pragma unroll 1
    for (int so = 0; so < YG_NS / 4; ++so) {
        int sb = so * 4;
        YG_STEP(sb + 0, 0, 0)
        YG_STEP(sb + 1, 1, 1)
        YG_STEP(sb + 2, 2, 0)
        YG_STEP(sb + 3, 3, 1)
    }

    if (emit) {
        sum += __shfl_xor(sum, 1); sum += __shfl_xor(sum, 2);
        ssq += __shfl_xor(ssq, 1); ssq += __shfl_xor(ssq, 2);
        if ((t & 3) == 0) {
            PS[kz * 16000 + grow] = sum;
            PQ[kz * 16000 + grow] = ssq;
        }
    }
    float* Pk = P + (size_t)kz * 16000 * 96;
#pragma unroll
    for (int m = 0; m < 2; m++)
#pragma unroll
        for (int n = 0; n < 3; n++)
#pragma unroll
            for (int j = 0; j < 4; j++) {
                int lr = wr + m * 16 + g * 4 + j;
                int c = wc + n * 16 + q;
                Pk[(size_t)(row0 + lr) * 96 + c] = acc[m][n][j];
            }
}

// ---------------------------------------------------------------- ygemm_stats
__global__ __launch_bounds__(256) void ygemm_stats(const float* __restrict__ PS,
                                                   const float* __restrict__ PQ,
                                                   float* __restrict__ INV,
                                                   float* __restrict__ NRM) {
    int r = blockIdx.x * 256 + threadIdx.x;
    if (r >= 16000) return;
    float s = PS[r] + PS[16000 + r];
    float qq = PQ[r] + PQ[16000 + r];
    INV[r] = (s == 0.0f) ? 0.0f : 1.0f / s;
    int img = r / N_BOX, n = r - img * N_BOX;
    NRM[(size_t)img * N_PAD + n] = sqrtf(qq);
}

// ---------------------------------------------------------------- ygemm_reduce
__global__ __launch_bounds__(256) void ygemm_reduce(const float* __restrict__ P,
                                                    const float* __restrict__ INV,
                                                    float* __restrict__ Y) {
    int gid = blockIdx.x * 256 + threadIdx.x;
    if (gid >= 16000 * 96) return;
    float s = P[gid] + P[gid + 1536000];
    Y[gid] = s * INV[gid / 96];
}

// ---------------------------------------------------------------- spmm1
__global__ __launch_bounds__(256) void spmm1(const u32* __restrict__ Aadj,
                                             const u32* __restrict__ Asim,
                                             const float* __restrict__ Y,
                                             const float* __restrict__ bc1,
                                             const float* __restrict__ bd1,
                                             float* __restrict__ H) {
    int gw = blockIdx.x * 4 + (threadIdx.x >> 6);
    int lane = threadIdx.x & 63;
    if (lane >= HIDN) return;
    int i = gw >> 1, br = gw & 1;
    int img = i / N_BOX, n = i % N_BOX;
    const u32* bp = (br ? Asim : Aadj) + ((size_t)img * N_PAD + n) * NWRD;
    const float* Yb = Y + (size_t)img * N_BOX * 96 + br * HIDN + lane;
    float acc = 0.0f;
    for (int w8 = 0; w8 < NWRD; w8++) {
        u32 wv = bp[w8];
        while (wv) {
            int s = __builtin_ctz(wv);
            wv &= wv - 1;
            acc += Yb[(size_t)(w8 * 32 + s) * 96];
        }
    }
    float bias = br ? bd1[lane] : bc1[lane];
    H[(size_t)i * 96 + br * HIDN + lane] = fmaxf(acc + bias, 0.0f);
}

// ---------------------------------------------------------------- gemm2
__global__ __launch_bounds__(256) void gemm2(const float* __restrict__ H,
                                             const float* __restrict__ Wc2,
                                             const float* __restrict__ Wd2,
                                             float* __restrict__ Z) {
    __shared__ float w2[2 * HIDN * NCLS];
    for (int idx = threadIdx.x; idx < 2 * HIDN * NCLS; idx += 256) {
        int br = idx / (HIDN * NCLS), e = idx % (HIDN * NCLS);
        w2[idx] = br ? Wd2[e] : Wc2[e];
    }
    __syncthreads();
    int gidx = blockIdx.x * 256 + threadIdx.x;
    if (gidx >= 16000 * 40) return;
    int i = gidx / 40, rem = gidx % 40;
    int br = rem / NCLS, c2 = rem % NCLS;
    const float* hrow = H + (size_t)i * 96 + br * HIDN;
    const float* wp = w2 + br * HIDN * NCLS;
    float acc = 0.0f;
#pragma unroll
    for (int h = 0; h < HIDN; h++) acc += hrow[h] * wp[h * NCLS + c2];
    Z[gidx] = acc;
}

// ---------------------------------------------------------------- spmm2 -> logits
__global__ __launch_bounds__(256) void spmm2(const u32* __restrict__ Aadj,
                                             const u32* __restrict__ Asim,
                                             const float* __restrict__ Z,
                                             const float* __restrict__ bc2,
                                             const float* __restrict__ bd2,
                                             float* __restrict__ out) {
    int gw = blockIdx.x * 4 + (threadIdx.x >> 6);
    int lane = threadIdx.x & 63;
    if (lane >= NCLS) return;
    int i = gw >> 1, br = gw & 1;
    int img = i / N_BOX, n = i % N_BOX;
    const u32* bp = (br ? Asim : Aadj) + ((size_t)img * N_PAD + n) * NWRD;
    const float* Zb = Z + (size_t)img * N_BOX * 40 + br * NCLS + lane;
    float acc = 0.0f;
    for (int w8 = 0; w8 < NWRD; w8++) {
        u32 wv = bp[w8];
        while (wv) {
            int s = __builtin_ctz(wv);
            wv &= wv - 1;
            acc += Zb[(size_t)(w8 * 32 + s) * 40];
        }
    }
    float logit = acc + (br ? bd2[lane] : bc2[lane]);
    out[(br ? 320000 : 0) + (size_t)i * NCLS + lane] = logit;
}

// ---------------------------------------------------------------- softmaxes
__global__ __launch_bounds__(256) void softmax_cls(float* __restrict__ out) {
    int i = blockIdx.x * 256 + threadIdx.x;
    if (i >= 16000) return;
    float* p = out + (size_t)i * NCLS;
    float m = p[0];
#pragma unroll
    for (int c = 1; c < NCLS; c++) m = fmaxf(m, p[c]);
    float e[NCLS], s = 0.0f;
#pragma unroll
    for (int c = 0; c < NCLS; c++) { e[c] = expf(p[c] - m); s += e[c]; }
    float inv = 1.0f / s;
#pragma unroll
    for (int c = 0; c < NCLS; c++) p[c] = e[c] * inv;
}

__global__ __launch_bounds__(256) void softmax_det(float* __restrict__ out) {
    __shared__ float vals[N_BOX];
    __shared__ float redm[4];
    __shared__ float reds[4];
    int img = blockIdx.x / NCLS, c = blockIdx.x % NCLS;
    float* base = out + 320000 + (size_t)img * N_BOX * NCLS + c;
    int t = threadIdx.x;
    float m = -3.4e38f;
    for (int n = t; n < N_BOX; n += 256) {
        float v = base[(size_t)n * NCLS];
        vals[n] = v;
        m = fmaxf(m, v);
    }
#pragma unroll
    for (int off = 32; off; off >>= 1) m = fmaxf(m, __shfl_down(m, off));
    if ((t & 63) == 0) redm[t >> 6] = m;
    __syncthreads();
    m = fmaxf(fmaxf(redm[0], redm[1]), fmaxf(redm[2], redm[3]));
    float s = 0.0f;
    for (int n = t; n < N_BOX; n += 256) s += expf(vals[n] - m);
#pragma unroll
    for (int off = 32; off; off >>= 1) s += __shfl_down(s, off);
    if ((t & 63) == 0) reds[t >> 6] = s;
    __syncthreads();
    s = reds[0] + reds[1] + reds[2] + reds[3];
    float inv = 1.0f / s;
    for (int n = t; n < N_BOX; n += 256) base[(size_t)n * NCLS] = expf(vals[n] - m) * inv;
}

// ---------------------------------------------------------------- launch
extern "C" void kernel_launch(void* const* d_in, const int* in_sizes, int n_in,
                              void* d_out, int out_size, void* d_ws, size_t ws_size,
                              hipStream_t stream) {
    const float* x1    = (const float*)d_in[0];
    const float* boxes = (const float*)d_in[2];
    const float* W_cls1 = (const float*)d_in[3];
    const float* b_cls1 = (const float*)d_in[4];
    const float* W_cls2 = (const float*)d_in[5];
    const float* b_cls2 = (const float*)d_in[6];
    const float* W_det1 = (const float*)d_in[7];
    const float* b_det1 = (const float*)d_in[8];
    const float* W_det2 = (const float*)d_in[9];
    const float* b_det2 = (const float*)d_in[10];
    float* out = (float*)d_out;

    char* ws = (char*)d_ws;
    size_t off = 0;
    auto alloc = [&](size_t bytes) -> void* {
        void* p = ws + off;
        off = (off + bytes + 255) & ~(size_t)255;
        return p;
    };
    u16* WTH   = (u16*)alloc((size_t)96 * C_DIM * 2);
    u16* WTL   = (u16*)alloc((size_t)96 * C_DIM * 2);
    float* INV = (float*)alloc((size_t)16000 * 4);
    float* NRM = (float*)alloc((size_t)B_IMG * N_PAD * 4);
    float* PS  = (float*)alloc((size_t)KSPLIT * 16000 * 4);
    float* PQ  = (float*)alloc((size_t)KSPLIT * 16000 * 4);
    u32* AADJ  = (u32*)alloc((size_t)B_IMG * N_PAD * NWRD * 4);
    u32* ASIM  = (u32*)alloc((size_t)B_IMG * N_PAD * NWRD * 4);
    float* Y   = (float*)alloc((size_t)16000 * 96 * 4);
    float* H   = (float*)alloc((size_t)16000 * 96 * 4);
    float* Z   = (float*)alloc((size_t)16000 * 40 * 4);
    float* P   = (float*)alloc((size_t)KSPLIT * 16000 * 96 * 4);
    size_t base_need = off;
    size_t sf_full = (size_t)B_IMG * N_PAD * C_DIM;   // fp8: 1 B/elem
    bool full = (ws_size >= base_need + sf_full);
    u8* SF = (u8*)alloc(full ? sf_full : (size_t)N_PAD * C_DIM);

    wt_build<<<dim3(1536), dim3(256), 0, stream>>>(W_cls1, W_det1, WTH, WTL);
    iou_bits<<<dim3(B_IMG * 500), dim3(256), 0, stream>>>(boxes, AADJ);

    if (full) {
        sf_pad<<<dim3(B_IMG * 48), dim3(256), 0, stream>>>(SF, NRM);
        ygemm_part<<<dim3(250, KSPLIT), dim3(256), 0, stream>>>(
            x1, WTH, WTL, SF, PS, PQ, P, 1);
        ygemm_stats<<<dim3(63), dim3(256), 0, stream>>>(PS, PQ, INV, NRM);
        gemm_sim<<<dim3(NPAIR, 1, B_IMG), dim3(256), 0, stream>>>(SF, NRM, ASIM);
        ygemm_reduce<<<dim3(6000), dim3(256), 0, stream>>>(P, INV, Y);
    } else {
        for (int b = 0; b < B_IMG; b++) {
            rowstats<<<dim3(N_PAD), dim3(256), 0, stream>>>(
                x1 + (size_t)b * N_BOX * C_DIM, INV + (size_t)b * N_BOX, SF,
                NRM + (size_t)b * N_PAD);
            gemm_sim<<<dim3(NPAIR, 1, 1), dim3(256), 0, stream>>>(
                SF, NRM + (size_t)b * N_PAD, ASIM + (size_t)b * N_PAD * NWRD);
        }
        ygemm_part<<<dim3(250, KSPLIT), dim3(256), 0, stream>>>(
            x1, WTH, WTL, SF, PS, PQ, P, 0);
        ygemm_reduce<<<dim3(6000), dim3(256), 0, stream>>>(P, INV, Y);
    }

    spmm1<<<dim3(8000), dim3(256), 0, stream>>>(AADJ, ASIM, Y, b_cls1, b_det1, H);
    gemm2<<<dim3(2500), dim3(256), 0, stream>>>(H, W_cls2, W_det2, Z);
    spmm2<<<dim3(8000), dim3(256), 0, stream>>>(AADJ, ASIM, Z, b_cls2, b_det2, out);
    softmax_cls<<<dim3(63), dim3(256), 0, stream>>>(out);
    softmax_det<<<dim3(160), dim3(256), 0, stream>>>(out);
    (void)in_sizes; (void)n_in; (void)out_size; (void)d_in; (void)ws_size;
}

// Round 12
// 466.598 us; speedup vs baseline: 1.2747x; 1.0071x over previous
//
#include <hip/hip_runtime.h>
#include <stdint.h>

typedef unsigned int u32;
typedef unsigned long long u64;
typedef unsigned short u16;
typedef unsigned char u8;

#define B_IMG 8
#define N_BOX 2000
#define N_PAD 2048
#define C_DIM 4096
#define HIDN 42
#define NCLS 20
#define NWRD 64   // 2048 bits per adjacency row
#define NPAIR 136 // 16*17/2 lower-triangle 128-tiles
#define KSPLIT 2
#define YG_NS 64   // (4096/KSPLIT)/32 steps per block

using f32x4 = __attribute__((ext_vector_type(4))) float;
using f32x16 = __attribute__((ext_vector_type(16))) float;
using s16x8 = __attribute__((ext_vector_type(8))) short;
using i32x8 = __attribute__((ext_vector_type(8))) int;

__device__ __forceinline__ u32 f2bf(float f) {   // fp32 -> bf16 RNE
    u32 u = __float_as_uint(f);
    u += 0x7FFFu + ((u >> 16) & 1u);
    return u >> 16;
}

#define GLOAD_LDS16(g, l)                                                     \
    __builtin_amdgcn_global_load_lds(                                         \
        (const __attribute__((address_space(1))) void*)(g),                   \
        (__attribute__((address_space(3))) void*)(l), 16, 0, 0)

// ---------------------------------------------------------------- wt_build
__global__ __launch_bounds__(256) void wt_build(const float* __restrict__ Wc,
                                                const float* __restrict__ Wd,
                                                u16* __restrict__ Wth,
                                                u16* __restrict__ Wtl) {
    int g = blockIdx.x * 256 + threadIdx.x;
    if (g >= 96 * C_DIM) return;
    int k = g & (C_DIM - 1);
    int c = g >> 12;
    float v = 0.0f;
    if (c < HIDN) v = Wc[k * HIDN + c];
    else if (c < 2 * HIDN) v = Wd[k * HIDN + (c - HIDN)];
    u32 hb = f2bf(v);
    float hf = __uint_as_float(hb << 16);
    u32 lb = f2bf(v - hf);
    Wth[g] = (u16)hb;
    Wtl[g] = (u16)lb;
}

// ---------------------------------------------------------------- sf_pad
__global__ __launch_bounds__(256) void sf_pad(u8* __restrict__ SF,
                                              float* __restrict__ NRM) {
    int row = blockIdx.x;                  // 0..383
    int img = row / 48, n = N_BOX + row % 48;
    uint4* p = (uint4*)(SF + ((size_t)img * N_PAD + n) * C_DIM);
    uint4 z = make_uint4(0, 0, 0, 0);
    p[threadIdx.x] = z;                    // 256 x 16B = 4096 B
    if (threadIdx.x == 0) NRM[(size_t)img * N_PAD + n] = 1e9f;
}

// ---------------------------------------------------------------- rowstats (fallback only)
__global__ __launch_bounds__(256) void rowstats(const float* __restrict__ x,
                                                float* __restrict__ inv_sum,
                                                u8* __restrict__ sf,
                                                float* __restrict__ nrm) {
    int r = blockIdx.x;
    int t = threadIdx.x;
    u8* sfrow = sf + (size_t)r * C_DIM;
    if (r >= N_BOX) {
        uint4 z = make_uint4(0, 0, 0, 0);
        uint4* p = (uint4*)sfrow;
        for (int i = t; i < C_DIM / 16; i += 256) p[i] = z;
        if (t == 0) nrm[r] = 1e9f;
        return;
    }
    const float4* xr = (const float4*)(x + (size_t)r * C_DIM);
    float4 v[4];
    float s = 0.0f, ss = 0.0f;
#pragma unroll
    for (int i = 0; i < 4; i++) {
        v[i] = xr[t + 256 * i];
        s += v[i].x + v[i].y + v[i].z + v[i].w;
        ss += v[i].x * v[i].x + v[i].y * v[i].y + v[i].z * v[i].z + v[i].w * v[i].w;
    }
    __shared__ float red[4][2];
#pragma unroll
    for (int off = 32; off; off >>= 1) {
        s += __shfl_down(s, off);
        ss += __shfl_down(ss, off);
    }
    int wid = t >> 6, lane = t & 63;
    if (lane == 0) { red[wid][0] = s; red[wid][1] = ss; }
    __syncthreads();
    s  = red[0][0] + red[1][0] + red[2][0] + red[3][0];
    ss = red[0][1] + red[1][1] + red[2][1] + red[3][1];
    if (t == 0) {
        inv_sum[r] = (s == 0.0f) ? 0.0f : 1.0f / s;
        nrm[r] = sqrtf(ss);
    }
    u32* sp = (u32*)sfrow;
#pragma unroll
    for (int i = 0; i < 4; i++) {
        float4 w = v[i];
        u32 pk = __builtin_amdgcn_cvt_pk_fp8_f32(4.f * w.x, 4.f * w.y, 0, false);
        pk = __builtin_amdgcn_cvt_pk_fp8_f32(4.f * w.z, 4.f * w.w, pk, true);
        sp[t + 256 * i] = pk;
    }
}

// ---------------------------------------------------------------- gemm_sim
// MX-scaled fp8 (unit scales): mfma_scale_f32_32x32x64_f8f6f4, fmt e4m3.
// BK=64 double-buffered single-barrier pipeline (unchanged staging volume).
// 16B-chunk XOR swizzle (c' = c ^ (r&3)) via pre-swizzled gload SOURCE +
// same XOR on the two b128 fragment reads (lane holds row l&31, 32B K-slice
// at byte (l>>5)*32). acc ~= 16*dot; bit = acc >= 8*nrm_r*nrm_c.
__global__ __launch_bounds__(256) void gemm_sim(const u8* __restrict__ sf_all,
                                                const float* __restrict__ nrm_all,
                                                u32* __restrict__ bits_all) {
    __shared__ __align__(16) char smem[32768];   // [A0 8K][B0 8K][A1 8K][B1 8K]
    char* tmat = smem;                           // epilogue reuse [128][132]

    int z = blockIdx.z;
    const u8* sf = sf_all + (size_t)z * N_PAD * C_DIM;
    const float* nrm = nrm_all + (size_t)z * N_PAD;
    u32* bits = bits_all + (size_t)z * N_PAD * NWRD;

    int p = blockIdx.x;
    int bi = (int)((sqrtf(8.0f * p + 1.0f) - 1.0f) * 0.5f);
    while (bi * (bi + 1) / 2 > p) bi--;
    while ((bi + 1) * (bi + 2) / 2 <= p) bi++;
    int bj = p - bi * (bi + 1) / 2;

    int t = threadIdx.x;
    int lane = t & 63;
    int w = t >> 6;
    int wm = w >> 1, wn = w & 1;         // wave owns 64x64 at (wm*64, wn*64)
    int l31 = lane & 31, ks = lane >> 5; // row-in-tile, K-half selector
    int tr0 = bi * 128, tc0 = bj * 128;
    f32x16 acc[2][2] = {};

    auto stage = [&](int it, int b) {
        int k0 = it * 64;
        u8* As = (u8*)smem + b * 16384;
        u8* Bs = As + 8192;
#pragma unroll
        for (int i = 0; i < 2; i++) {
            int ci = t + 256 * i;            // 0..511 16B-chunks
            int r = ci >> 2, c16 = ci & 3;
            int sc16 = c16 ^ (r & 3);        // inverse-swizzled source chunk
            GLOAD_LDS16(sf + ((size_t)(tr0 + r) << 12) + k0 + sc16 * 16,
                        As + ci * 16);
            GLOAD_LDS16(sf + ((size_t)(tc0 + r) << 12) + k0 + sc16 * 16,
                        Bs + ci * 16);
        }
    };

    stage(0, 0);
    __syncthreads();
    for (int it = 0; it < 64; ++it) {
        int cur = it & 1;
        if (it + 1 < 64) stage(it + 1, cur ^ 1);   // prefetch under MFMA
        const u8* As = (const u8*)smem + cur * 16384;
        const u8* Bs = As + 8192;
        i32x8 a[2], b[2];
#pragma unroll
        for (int mt = 0; mt < 2; mt++) {
            int row = wm * 64 + mt * 32 + l31;
            int sw = row & 3;
            int4 lo = *(const int4*)(As + row * 64 + ((2 * ks + 0) ^ sw) * 16);
            int4 hi = *(const int4*)(As + row * 64 + ((2 * ks + 1) ^ sw) * 16);
            a[mt][0] = lo.x; a[mt][1] = lo.y; a[mt][2] = lo.z; a[mt][3] = lo.w;
            a[mt][4] = hi.x; a[mt][5] = hi.y; a[mt][6] = hi.z; a[mt][7] = hi.w;
        }
#pragma unroll
        for (int nt = 0; nt < 2; nt++) {
            int row = wn * 64 + nt * 32 + l31;
            int sw = row & 3;
            int4 lo = *(const int4*)(Bs + row * 64 + ((2 * ks + 0) ^ sw) * 16);
            int4 hi = *(const int4*)(Bs + row * 64 + ((2 * ks + 1) ^ sw) * 16);
            b[nt][0] = lo.x; b[nt][1] = lo.y; b[nt][2] = lo.z; b[nt][3] = lo.w;
            b[nt][4] = hi.x; b[nt][5] = hi.y; b[nt][6] = hi.z; b[nt][7] = hi.w;
        }
#pragma unroll
        for (int mt = 0; mt < 2; mt++)
#pragma unroll
            for (int nt = 0; nt < 2; nt++)
                acc[mt][nt] = __builtin_amdgcn_mfma_scale_f32_32x32x64_f8f6f4(
                    a[mt], b[nt], acc[mt][nt], 0, 0,
                    0, 0x7F7F7F7F, 0, 0x7F7F7F7F);   // unit e8m0 scales
        __syncthreads();
    }

    // epilogue: 32x32 C/D layout col=lane&31, row=(reg&3)+8*(reg>>2)+4*(lane>>5)
#pragma unroll
    for (int mt = 0; mt < 2; mt++)
#pragma unroll
        for (int nt = 0; nt < 2; nt++) {
            int col = wn * 64 + nt * 32 + l31;
            float nc8 = 8.0f * nrm[tc0 + col];
#pragma unroll
            for (int reg = 0; reg < 16; reg++) {
                int row = wm * 64 + mt * 32 + (reg & 3) + 8 * (reg >> 2) + 4 * ks;
                float thr = nc8 * nrm[tr0 + row];
                tmat[row * 132 + col] = (acc[mt][nt][reg] >= thr) ? 1 : 0;
            }
        }
    __syncthreads();

    for (int rr = 0; rr < 32; rr++) {
        int row = w * 32 + rr;
#pragma unroll
        for (int h = 0; h < 2; h++) {
            u64 b2 = __ballot(tmat[row * 132 + h * 64 + lane] != 0);
            if (lane < 2)
                bits[(size_t)(tr0 + row) * NWRD + bj * 4 + 2 * h + lane] = (u32)(b2 >> (32 * lane));
        }
    }
    if (bi != bj) {
        for (int rr = 0; rr < 32; rr++) {
            int c = w * 32 + rr;
#pragma unroll
            for (int h = 0; h < 2; h++) {
                u64 b2 = __ballot(tmat[(h * 64 + lane) * 132 + c] != 0);
                if (lane < 2)
                    bits[(size_t)(tc0 + c) * NWRD + bi * 4 + 2 * h + lane] = (u32)(b2 >> (32 * lane));
            }
        }
    }
}

// ---------------------------------------------------------------- iou_bits
__global__ __launch_bounds__(256) void iou_bits(const float* __restrict__ boxes,
                                                u32* __restrict__ bits) {
    __shared__ float bx[N_BOX * 4];
    int blk = blockIdx.x;
    int img = blk / 500;
    int r0 = (blk % 500) * 4;
    const float* bb = boxes + (size_t)img * N_BOX * 4;
    for (int i = threadIdx.x; i < N_BOX * 4; i += 256) bx[i] = bb[i];
    __syncthreads();
    int t = threadIdx.x;
    int ri = r0 + (t >> 6);
    int wi = t & 63;
    float x1a = bx[ri * 4 + 0], y1a = bx[ri * 4 + 1];
    float x2a = bx[ri * 4 + 2], y2a = bx[ri * 4 + 3];
    float areaA = __fmul_rn(__fsub_rn(x2a, x1a), __fsub_rn(y2a, y1a));
    u32 wv = 0;
    int jb = wi * 32;
#pragma unroll 4
    for (int s = 0; s < 32; s++) {
        int j = jb + s;
        if (j < N_BOX) {
            float x1b = bx[j * 4 + 0], y1b = bx[j * 4 + 1];
            float x2b = bx[j * 4 + 2], y2b = bx[j * 4 + 3];
            float areaB = __fmul_rn(__fsub_rn(x2b, x1b), __fsub_rn(y2b, y1b));
            float ltx = fmaxf(x1a, x1b), lty = fmaxf(y1a, y1b);
            float rbx = fminf(x2a, x2b), rby = fminf(y2a, y2b);
            float wx = fmaxf(__fsub_rn(rbx, ltx), 0.0f);
            float wy = fmaxf(__fsub_rn(rby, lty), 0.0f);
            float inter = __fmul_rn(wx, wy);
            float uni = __fsub_rn(__fadd_rn(areaA, areaB), inter);
            float iou = __fdiv_rn(inter, fmaxf(uni, 1e-12f));
            if (iou >= 0.5f) wv |= (1u << s);
        }
    }
    bits[((size_t)img * N_PAD + ri) * NWRD + wi] = wv;
}

// ---------------------------------------------------------------- ygemm_part
#define YG_STEP(s_, d, bufc)                                                  \
    {                                                                         \
        float4 a0 = pa[d][0], a1 = pa[d][1];                                  \
        float e[8] = {a0.x, a0.y, a0.z, a0.w, a1.x, a1.y, a1.z, a1.w};        \
        if (emit) {                                                           \
            sum += e[0] + e[1] + e[2] + e[3] + e[4] + e[5] + e[6] + e[7];     \
            ssq += e[0]*e[0] + e[1]*e[1] + e[2]*e[2] + e[3]*e[3] +            \
                   e[4]*e[4] + e[5]*e[5] + e[6]*e[6] + e[7]*e[7];             \
            u32 lo = __builtin_amdgcn_cvt_pk_fp8_f32(4.f*e[0], 4.f*e[1], 0, false); \
            lo = __builtin_amdgcn_cvt_pk_fp8_f32(4.f*e[2], 4.f*e[3], lo, true);     \
            u32 hi = __builtin_amdgcn_cvt_pk_fp8_f32(4.f*e[4], 4.f*e[5], 0, false); \
            hi = __builtin_amdgcn_cvt_pk_fp8_f32(4.f*e[6], 4.f*e[7], hi, true);     \
            *(uint2*)(sfp + (size_t)(s_) * 32) = make_uint2(lo, hi);          \
        }                                                                     \
        u32 hb[8], lb[8];                                                     \
        _Pragma("unroll")                                                     \
        for (int j2 = 0; j2 < 8; j2++) {                                      \
            hb[j2] = f2bf(e[j2]);                                             \
            float hf = __uint_as_float(hb[j2] << 16);                         \
            lb[j2] = f2bf(e[j2] - hf);                                        \
        }                                                                     \
        *(uint4*)&Ah[bufc][t * 8] = make_uint4(hb[0]|(hb[1]<<16), hb[2]|(hb[3]<<16), \
                                               hb[4]|(hb[5]<<16), hb[6]|(hb[7]<<16)); \
        *(uint4*)&Al[bufc][t * 8] = make_uint4(lb[0]|(lb[1]<<16), lb[2]|(lb[3]<<16), \
                                               lb[4]|(lb[5]<<16), lb[6]|(lb[7]<<16)); \
        __syncthreads();                                                      \
        if ((s_) + 1 < YG_NS) stage_B((s_) + 1, (bufc) ^ 1);                  \
        if ((s_) + 4 < YG_NS) {                                               \
            pa[d][0] = *(const float4*)(xrow + ((s_) + 4) * 32);              \
            pa[d][1] = *(const float4*)(xrow + ((s_) + 4) * 32 + 4);          \
        }                                                                     \
        s16x8 fah[2], fal[2], fbh[3], fbl[3];                                 \
        _Pragma("unroll")                                                     \
        for (int m = 0; m < 2; m++) {                                         \
            fah[m] = *(const s16x8*)&Ah[bufc][(wr + m * 16 + q) * 32 + g * 8]; \
            fal[m] = *(const s16x8*)&Al[bufc][(wr + m * 16 + q) * 32 + g * 8]; \
        }                                                                     \
        _Pragma("unroll")                                                     \
        for (int n = 0; n < 3; n++) {                                         \
            fbh[n] = *(const s16x8*)&Bh[bufc][(wc + n * 16 + q) * 32 + g * 8]; \
            fbl[n] = *(const s16x8*)&Bl[bufc][(wc + n * 16 + q) * 32 + g * 8]; \
        }                                                                     \
        _Pragma("unroll")                                                     \
        for (int m = 0; m < 2; m++)                                           \
            _Pragma("unroll")                                                 \
            for (int n = 0; n < 3; n++) {                                     \
                acc[m][n] = __builtin_amdgcn_mfma_f32_16x16x32_bf16(fah[m], fbh[n], acc[m][n], 0, 0, 0); \
                acc[m][n] = __builtin_amdgcn_mfma_f32_16x16x32_bf16(fal[m], fbh[n], acc[m][n], 0, 0, 0); \
                acc[m][n] = __builtin_amdgcn_mfma_f32_16x16x32_bf16(fah[m], fbl[n], acc[m][n], 0, 0, 0); \
            }                                                                 \
    }

__global__ __launch_bounds__(256) void ygemm_part(const float* __restrict__ x,
                                                  const u16* __restrict__ Wh,
                                                  const u16* __restrict__ Wl,
                                                  u8* __restrict__ SF,
                                                  float* __restrict__ PS,
                                                  float* __restrict__ PQ,
                                                  float* __restrict__ P,
                                                  int emit) {
    __shared__ u16 Ah[2][64 * 32];
    __shared__ u16 Al[2][64 * 32];
    __shared__ u16 Bh[2][96 * 32];
    __shared__ u16 Bl[2][96 * 32];

    int t = threadIdx.x;
    int row0 = blockIdx.x * 64;
    int kz = blockIdx.y;
    int ks0 = kz * (C_DIM / KSPLIT);
    int ar = t >> 2;                       // staging row 0..63
    int grow = row0 + ar;
    int img = grow / N_BOX, nrow = grow - img * N_BOX;
    const float* xrow = x + (size_t)grow * C_DIM + ks0 + (t & 3) * 8;
    u8* sfp = SF + ((size_t)img * N_PAD + nrow) * C_DIM + ks0 + (t & 3) * 8;

    int w = t >> 6, lane = t & 63;
    int q = lane & 15, g = lane >> 4;
    int wr = (w & 1) * 32, wc = (w >> 1) * 48;

    f32x4 acc[2][3] = {};
    float sum = 0.0f, ssq = 0.0f;

    auto stage_B = [&](int sstep, int b) {
        int ks = ks0 + sstep * 32;
#pragma unroll
        for (int i = 0; i < 3; i++) {
            int idx = t + 256 * i;
            int half = idx >= 384;
            int loc = half ? idx - 384 : idx;
            int cr = loc >> 2, kc2 = loc & 3;
            const u16* src = (half ? Wl : Wh) + (size_t)cr * C_DIM + ks + kc2 * 8;
            u16* dst = (half ? Bl[b] : Bh[b]) + loc * 8;
            GLOAD_LDS16(src, dst);
        }
    };

    float4 pa[4][2];
#pragma unroll
    for (int d = 0; d < 4; d++) {
        pa[d][0] = *(const float4*)(xrow + d * 32);
        pa[d][1] = *(const float4*)(xrow + d * 32 + 4);
    }
    stage_B(0, 0);

#pragma unroll 1
    for (int so = 0; so < YG_NS / 4; ++so) {
        int sb = so * 4;
        YG_STEP(sb + 0, 0, 0)
        YG_STEP(sb + 1, 1, 1)
        YG_STEP(sb + 2, 2, 0)
        YG_STEP(sb + 3, 3, 1)
    }

    if (emit) {
        sum += __shfl_xor(sum, 1); sum += __shfl_xor(sum, 2);
        ssq += __shfl_xor(ssq, 1); ssq += __shfl_xor(ssq, 2);
        if ((t & 3) == 0) {
            PS[kz * 16000 + grow] = sum;
            PQ[kz * 16000 + grow] = ssq;
        }
    }
    float* Pk = P + (size_t)kz * 16000 * 96;
#pragma unroll
    for (int m = 0; m < 2; m++)
#pragma unroll
        for (int n = 0; n < 3; n++)
#pragma unroll
            for (int j = 0; j < 4; j++) {
                int lr = wr + m * 16 + g * 4 + j;
                int c = wc + n * 16 + q;
                Pk[(size_t)(row0 + lr) * 96 + c] = acc[m][n][j];
            }
}

// ---------------------------------------------------------------- ygemm_stats
__global__ __launch_bounds__(256) void ygemm_stats(const float* __restrict__ PS,
                                                   const float* __restrict__ PQ,
                                                   float* __restrict__ INV,
                                                   float* __restrict__ NRM) {
    int r = blockIdx.x * 256 + threadIdx.x;
    if (r >= 16000) return;
    float s = PS[r] + PS[16000 + r];
    float qq = PQ[r] + PQ[16000 + r];
    INV[r] = (s == 0.0f) ? 0.0f : 1.0f / s;
    int img = r / N_BOX, n = r - img * N_BOX;
    NRM[(size_t)img * N_PAD + n] = sqrtf(qq);
}

// ---------------------------------------------------------------- ygemm_reduce
__global__ __launch_bounds__(256) void ygemm_reduce(const float* __restrict__ P,
                                                    const float* __restrict__ INV,
                                                    float* __restrict__ Y) {
    int gid = blockIdx.x * 256 + threadIdx.x;
    if (gid >= 16000 * 96) return;
    float s = P[gid] + P[gid + 1536000];
    Y[gid] = s * INV[gid / 96];
}

// ---------------------------------------------------------------- spmm1
__global__ __launch_bounds__(256) void spmm1(const u32* __restrict__ Aadj,
                                             const u32* __restrict__ Asim,
                                             const float* __restrict__ Y,
                                             const float* __restrict__ bc1,
                                             const float* __restrict__ bd1,
                                             float* __restrict__ H) {
    int gw = blockIdx.x * 4 + (threadIdx.x >> 6);
    int lane = threadIdx.x & 63;
    if (lane >= HIDN) return;
    int i = gw >> 1, br = gw & 1;
    int img = i / N_BOX, n = i % N_BOX;
    const u32* bp = (br ? Asim : Aadj) + ((size_t)img * N_PAD + n) * NWRD;
    const float* Yb = Y + (size_t)img * N_BOX * 96 + br * HIDN + lane;
    float acc = 0.0f;
    for (int w8 = 0; w8 < NWRD; w8++) {
        u32 wv = bp[w8];
        while (wv) {
            int s = __builtin_ctz(wv);
            wv &= wv - 1;
            acc += Yb[(size_t)(w8 * 32 + s) * 96];
        }
    }
    float bias = br ? bd1[lane] : bc1[lane];
    H[(size_t)i * 96 + br * HIDN + lane] = fmaxf(acc + bias, 0.0f);
}

// ---------------------------------------------------------------- gemm2
__global__ __launch_bounds__(256) void gemm2(const float* __restrict__ H,
                                             const float* __restrict__ Wc2,
                                             const float* __restrict__ Wd2,
                                             float* __restrict__ Z) {
    __shared__ float w2[2 * HIDN * NCLS];
    for (int idx = threadIdx.x; idx < 2 * HIDN * NCLS; idx += 256) {
        int br = idx / (HIDN * NCLS), e = idx % (HIDN * NCLS);
        w2[idx] = br ? Wd2[e] : Wc2[e];
    }
    __syncthreads();
    int gidx = blockIdx.x * 256 + threadIdx.x;
    if (gidx >= 16000 * 40) return;
    int i = gidx / 40, rem = gidx % 40;
    int br = rem / NCLS, c2 = rem % NCLS;
    const float* hrow = H + (size_t)i * 96 + br * HIDN;
    const float* wp = w2 + br * HIDN * NCLS;
    float acc = 0.0f;
#pragma unroll
    for (int h = 0; h < HIDN; h++) acc += hrow[h] * wp[h * NCLS + c2];
    Z[gidx] = acc;
}

// ---------------------------------------------------------------- spmm2 -> logits
__global__ __launch_bounds__(256) void spmm2(const u32* __restrict__ Aadj,
                                             const u32* __restrict__ Asim,
                                             const float* __restrict__ Z,
                                             const float* __restrict__ bc2,
                                             const float* __restrict__ bd2,
                                             float* __restrict__ out) {
    int gw = blockIdx.x * 4 + (threadIdx.x >> 6);
    int lane = threadIdx.x & 63;
    if (lane >= NCLS) return;
    int i = gw >> 1, br = gw & 1;
    int img = i / N_BOX, n = i % N_BOX;
    const u32* bp = (br ? Asim : Aadj) + ((size_t)img * N_PAD + n) * NWRD;
    const float* Zb = Z + (size_t)img * N_BOX * 40 + br * NCLS + lane;
    float acc = 0.0f;
    for (int w8 = 0; w8 < NWRD; w8++) {
        u32 wv = bp[w8];
        while (wv) {
            int s = __builtin_ctz(wv);
            wv &= wv - 1;
            acc += Zb[(size_t)(w8 * 32 + s) * 40];
        }
    }
    float logit = acc + (br ? bd2[lane] : bc2[lane]);
    out[(br ? 320000 : 0) + (size_t)i * NCLS + lane] = logit;
}

// ---------------------------------------------------------------- softmaxes
__global__ __launch_bounds__(256) void softmax_cls(float* __restrict__ out) {
    int i = blockIdx.x * 256 + threadIdx.x;
    if (i >= 16000) return;
    float* p = out + (size_t)i * NCLS;
    float m = p[0];
#pragma unroll
    for (int c = 1; c < NCLS; c++) m = fmaxf(m, p[c]);
    float e[NCLS], s = 0.0f;
#pragma unroll
    for (int c = 0; c < NCLS; c++) { e[c] = expf(p[c] - m); s += e[c]; }
    float inv = 1.0f / s;
#pragma unroll
    for (int c = 0; c < NCLS; c++) p[c] = e[c] * inv;
}

__global__ __launch_bounds__(256) void softmax_det(float* __restrict__ out) {
    __shared__ float vals[N_BOX];
    __shared__ float redm[4];
    __shared__ float reds[4];
    int img = blockIdx.x / NCLS, c = blockIdx.x % NCLS;
    float* base = out + 320000 + (size_t)img * N_BOX * NCLS + c;
    int t = threadIdx.x;
    float m = -3.4e38f;
    for (int n = t; n < N_BOX; n += 256) {
        float v = base[(size_t)n * NCLS];
        vals[n] = v;
        m = fmaxf(m, v);
    }
#pragma unroll
    for (int off = 32; off; off >>= 1) m = fmaxf(m, __shfl_down(m, off));
    if ((t & 63) == 0) redm[t >> 6] = m;
    __syncthreads();
    m = fmaxf(fmaxf(redm[0], redm[1]), fmaxf(redm[2], redm[3]));
    float s = 0.0f;
    for (int n = t; n < N_BOX; n += 256) s += expf(vals[n] - m);
#pragma unroll
    for (int off = 32; off; off >>= 1) s += __shfl_down(s, off);
    if ((t & 63) == 0) reds[t >> 6] = s;
    __syncthreads();
    s = reds[0] + reds[1] + reds[2] + reds[3];
    float inv = 1.0f / s;
    for (int n = t; n < N_BOX; n += 256) base[(size_t)n * NCLS] = expf(vals[n] - m) * inv;
}

// ---------------------------------------------------------------- launch
extern "C" void kernel_launch(void* const* d_in, const int* in_sizes, int n_in,
                              void* d_out, int out_size, void* d_ws, size_t ws_size,
                              hipStream_t stream) {
    const float* x1    = (const float*)d_in[0];
    const float* boxes = (const float*)d_in[2];
    const float* W_cls1 = (const float*)d_in[3];
    const float* b_cls1 = (const float*)d_in[4];
    const float* W_cls2 = (const float*)d_in[5];
    const float* b_cls2 = (const float*)d_in[6];
    const float* W_det1 = (const float*)d_in[7];
    const float* b_det1 = (const float*)d_in[8];
    const float* W_det2 = (const float*)d_in[9];
    const float* b_det2 = (const float*)d_in[10];
    float* out = (float*)d_out;

    char* ws = (char*)d_ws;
    size_t off = 0;
    auto alloc = [&](size_t bytes) -> void* {
        void* p = ws + off;
        off = (off + bytes + 255) & ~(size_t)255;
        return p;
    };
    u16* WTH   = (u16*)alloc((size_t)96 * C_DIM * 2);
    u16* WTL   = (u16*)alloc((size_t)96 * C_DIM * 2);
    float* INV = (float*)alloc((size_t)16000 * 4);
    float* NRM = (float*)alloc((size_t)B_IMG * N_PAD * 4);
    float* PS  = (float*)alloc((size_t)KSPLIT * 16000 * 4);
    float* PQ  = (float*)alloc((size_t)KSPLIT * 16000 * 4);
    u32* AADJ  = (u32*)alloc((size_t)B_IMG * N_PAD * NWRD * 4);
    u32* ASIM  = (u32*)alloc((size_t)B_IMG * N_PAD * NWRD * 4);
    float* Y   = (float*)alloc((size_t)16000 * 96 * 4);
    float* H   = (float*)alloc((size_t)16000 * 96 * 4);
    float* Z   = (float*)alloc((size_t)16000 * 40 * 4);
    float* P   = (float*)alloc((size_t)KSPLIT * 16000 * 96 * 4);
    size_t base_need = off;
    size_t sf_full = (size_t)B_IMG * N_PAD * C_DIM;   // fp8: 1 B/elem
    bool full = (ws_size >= base_need + sf_full);
    u8* SF = (u8*)alloc(full ? sf_full : (size_t)N_PAD * C_DIM);

    wt_build<<<dim3(1536), dim3(256), 0, stream>>>(W_cls1, W_det1, WTH, WTL);
    iou_bits<<<dim3(B_IMG * 500), dim3(256), 0, stream>>>(boxes, AADJ);

    if (full) {
        sf_pad<<<dim3(B_IMG * 48), dim3(256), 0, stream>>>(SF, NRM);
        ygemm_part<<<dim3(250, KSPLIT), dim3(256), 0, stream>>>(
            x1, WTH, WTL, SF, PS, PQ, P, 1);
        ygemm_stats<<<dim3(63), dim3(256), 0, stream>>>(PS, PQ, INV, NRM);
        gemm_sim<<<dim3(NPAIR, 1, B_IMG), dim3(256), 0, stream>>>(SF, NRM, ASIM);
        ygemm_reduce<<<dim3(6000), dim3(256), 0, stream>>>(P, INV, Y);
    } else {
        for (int b = 0; b < B_IMG; b++) {
            rowstats<<<dim3(N_PAD), dim3(256), 0, stream>>>(
                x1 + (size_t)b * N_BOX * C_DIM, INV + (size_t)b * N_BOX, SF,
                NRM + (size_t)b * N_PAD);
            gemm_sim<<<dim3(NPAIR, 1, 1), dim3(256), 0, stream>>>(
                SF, NRM + (size_t)b * N_PAD, ASIM + (size_t)b * N_PAD * NWRD);
        }
        ygemm_part<<<dim3(250, KSPLIT), dim3(256), 0, stream>>>(
            x1, WTH, WTL, SF, PS, PQ, P, 0);
        ygemm_reduce<<<dim3(6000), dim3(256), 0, stream>>>(P, INV, Y);
    }

    spmm1<<<dim3(8000), dim3(256), 0, stream>>>(AADJ, ASIM, Y, b_cls1, b_det1, H);
    gemm2<<<dim3(2500), dim3(256), 0, stream>>>(H, W_cls2, W_det2, Z);
    spmm2<<<dim3(8000), dim3(256), 0, stream>>>(AADJ, ASIM, Z, b_cls2, b_det2, out);
    softmax_cls<<<dim3(63), dim3(256), 0, stream>>>(out);
    softmax_det<<<dim3(160), dim3(256), 0, stream>>>(out);
    (void)in_sizes; (void)n_in; (void)out_size; (void)d_in; (void)ws_size;
}